// Round 1
// baseline (177.476 us; speedup 1.0000x reference)
//
#include <hip/hip_runtime.h>
#include <hip/hip_bf16.h>

typedef __attribute__((ext_vector_type(4))) float f32x4;
typedef __attribute__((ext_vector_type(8))) short s16x8;
typedef __attribute__((ext_vector_type(4))) short s16x4;

#define DEV static __device__ __forceinline__

// fp32 -> bf16 round-to-nearest-even
DEV unsigned short f2bf(float f) {
    unsigned int u = __builtin_bit_cast(unsigned int, f);
    u += 0x7fffu + ((u >> 16) & 1u);
    return (unsigned short)(u >> 16);
}

#if __has_builtin(__builtin_amdgcn_exp2f)
#define EXP2(x) __builtin_amdgcn_exp2f(x)
#else
#define EXP2(x) exp2f(x)
#endif

// pack two fp32 -> two truncated bf16 in one dword (low short = a, high = b)
DEV unsigned int pack2(float a, float b) {
#if __has_builtin(__builtin_amdgcn_perm)
    return __builtin_amdgcn_perm(__builtin_bit_cast(unsigned int, b),
                                 __builtin_bit_cast(unsigned int, a), 0x07060302u);
#else
    return (__builtin_bit_cast(unsigned int, a) >> 16) |
           (__builtin_bit_cast(unsigned int, b) & 0xffff0000u);
#endif
}

// 8 bf16 from LDS via two 8B reads (padded strides: only 8B alignment)
DEV s16x8 ld8(const unsigned short* p) {
    s16x4 lo = *(const s16x4*)(p);
    s16x4 hi = *(const s16x4*)(p + 4);
    return __builtin_shufflevector(lo, hi, 0, 1, 2, 3, 4, 5, 6, 7);
}
// 16B-aligned single b128 read
DEV s16x8 ld8a(const unsigned short* p) { return *(const s16x8*)p; }

DEV f32x4 mfma16(s16x8 a, s16x8 b, f32x4 c) {
    return __builtin_amdgcn_mfma_f32_16x16x32_bf16(a, b, c, 0, 0, 0);
}

// async global->LDS, 16B per lane; lds dest = wave-uniform base + lane*16
DEV void glds16(const unsigned short* g, unsigned short* l) {
    __builtin_amdgcn_global_load_lds(
        (const __attribute__((address_space(1))) unsigned int*)g,
        (__attribute__((address_space(3))) unsigned int*)l, 16, 0, 0);
}

// ---------------------------------------------------------------------------
// fp32 -> bf16 bulk cast over two disjoint regions (one launch)
// ---------------------------------------------------------------------------
__global__ __launch_bounds__(256) void convf2b2(
        const float* __restrict__ s0, unsigned short* __restrict__ d0, int n40,
        const float* __restrict__ s1, unsigned short* __restrict__ d1, int n41) {
    int i = blockIdx.x * 256 + threadIdx.x;
    if (i < n40) {
        float4 v = ((const float4*)s0)[i];
        s16x4 o = {(short)f2bf(v.x), (short)f2bf(v.y), (short)f2bf(v.z), (short)f2bf(v.w)};
        ((s16x4*)d0)[i] = o;
    } else if (i - n40 < n41) {
        int j = i - n40;
        float4 v = ((const float4*)s1)[j];
        s16x4 o = {(short)f2bf(v.x), (short)f2bf(v.y), (short)f2bf(v.z), (short)f2bf(v.w)};
        ((s16x4*)d1)[j] = o;
    }
}

__global__ __launch_bounds__(256) void convf2b(const float* __restrict__ s,
                                               unsigned short* __restrict__ d, int n4) {
    int i = blockIdx.x * 256 + threadIdx.x;
    if (i < n4) {
        float4 v = ((const float4*)s)[i];
        s16x4 o = {(short)f2bf(v.x), (short)f2bf(v.y), (short)f2bf(v.z), (short)f2bf(v.w)};
        ((s16x4*)d)[i] = o;
    }
}

// ---------------------------------------------------------------------------
// QKV projection: C[4096][3072] = Xb[4096][1024](bf16) * Wq[3072][1024](bf16)^T
// 512 threads = 8 waves, wave tile 32x64 (acc[2][4]). 128x128 block, BK=64.
// 24 waves/CU (3 blocks) for barrier-drain hiding via cross-wave overlap.
// ---------------------------------------------------------------------------
__global__ __launch_bounds__(512) void qkv_gemm(
        const unsigned short* __restrict__ Xb, const unsigned short* __restrict__ Wq,
        unsigned short* __restrict__ q_ws, unsigned short* __restrict__ k_ws,
        unsigned short* __restrict__ v_ws) {
    __shared__ unsigned short As[2][128 * 32];
    __shared__ unsigned short Bs[2][128 * 32];
    const int tid = threadIdx.x, lane = tid & 63, wave = tid >> 6;  // 0..7
    const int l15 = lane & 15, l4 = lane >> 4;
    const int wm = (wave >> 1) * 32, wn = (wave & 1) * 64;
    const int m0 = blockIdx.y * 128, n0 = blockIdx.x * 128;

    f32x4 acc[2][4];
    for (int i = 0; i < 2; i++)
        for (int j = 0; j < 4; j++) acc[i][j] = (f32x4){0.f, 0.f, 0.f, 0.f};

    // wave stages A rows [wave*16, +16) and B rows [wave*16, +16), both halves
    const unsigned short* aptr = &Xb[(size_t)(m0 + wave * 16 + (lane >> 2)) * 1024 + (lane & 3) * 8];
    const unsigned short* bptr = &Wq[(size_t)(n0 + wave * 16 + (lane >> 2)) * 1024 + (lane & 3) * 8];

    for (int k0 = 0; k0 < 1024; k0 += 64) {
        __syncthreads();
        for (int c = 0; c < 2; c++) {
            glds16(aptr + k0 + c * 32, &As[c][(wave * 16) * 32]);
            glds16(bptr + k0 + c * 32, &Bs[c][(wave * 16) * 32]);
        }
        __syncthreads();
        for (int c = 0; c < 2; c++) {
            s16x8 af[2], bf[4];
            for (int mt = 0; mt < 2; mt++) af[mt] = ld8a(&As[c][(wm + mt * 16 + l15) * 32 + l4 * 8]);
            for (int nt = 0; nt < 4; nt++) bf[nt] = ld8a(&Bs[c][(wn + nt * 16 + l15) * 32 + l4 * 8]);
            for (int mt = 0; mt < 2; mt++)
                for (int nt = 0; nt < 4; nt++)
                    acc[mt][nt] = mfma16(af[mt], bf[nt], acc[mt][nt]);
        }
    }

    // epilogue (C/D layout: row=(lane>>4)*4+reg, col=lane&15)
    const int gnb = n0 + wn;  // 64-aligned -> one (which, head) per wave
    const int which = gnb >> 10, h = (gnb >> 6) & 15;
    const int bidx = m0 >> 11, tb = m0 & 2047;
    if (which == 2) {
        // V transposed: v_ws[bh][dh][t], 4 consecutive t per lane -> 8B store
        unsigned short* dst = v_ws + (size_t)(bidx * 16 + h) * 64 * 2048;
        for (int mt = 0; mt < 2; mt++) {
            int t = tb + wm + mt * 16 + l4 * 4;
            for (int nt = 0; nt < 4; nt++) {
                int dh = nt * 16 + l15;
                s16x4 pp;
                for (int r = 0; r < 4; r++) pp[r] = (short)f2bf(acc[mt][nt][r]);
                *(s16x4*)&dst[(size_t)dh * 2048 + t] = pp;
            }
        }
    } else {
        unsigned short* dst = ((which == 0) ? q_ws : k_ws) + (size_t)(bidx * 16 + h) * 2048 * 64;
        // q folded scale: Dh^-0.5 * log2(e) so attention uses raw exp2
        const float sc = (which == 0) ? 0.18033688f : 1.0f;
        for (int mt = 0; mt < 2; mt++) {
            int t0 = tb + wm + mt * 16 + l4 * 4;
            for (int nt = 0; nt < 4; nt++) {
                int dh = nt * 16 + l15;
                for (int r = 0; r < 4; r++)
                    dst[(size_t)(t0 + r) * 64 + dh] = f2bf(acc[mt][nt][r] * sc);
            }
        }
    }
}

// ---------------------------------------------------------------------------
// Causal flash attention v8: 4 waves x 32 q-rows each (was 8 x 16).
// Each K/V LDS fragment now feeds TWO MFMAs (q-subtile pair) -> LDS bytes
// per MFMA drop ~40%. Block = 256 threads, 128 q-rows, grid (32,16) = 512
// blocks = 2/CU all-resident. q-tile remap pairs tile i with tile 15-i on
// the same CU (blocks c and c+256) -> constant 36 k-iterations per CU
// instead of 20..48.
// ---------------------------------------------------------------------------
__global__ __launch_bounds__(256) void attn(
        const unsigned short* __restrict__ q_ws, const unsigned short* __restrict__ k_ws,
        const unsigned short* __restrict__ v_ws, unsigned short* __restrict__ ao) {
    constexpr int LDP = 68;  // dword stride 34 -> cheap 2-way
    __shared__ unsigned short Ks[2][2][64 * 32];  // [buf][d-half][key][32 d]
    __shared__ unsigned short Vt[2][2][64 * 32];  // [buf][key-half][d][32 key]
    __shared__ unsigned short Ps[4 * 32 * LDP];   // per-wave P / epilogue O (32 rows)
    const int tid = threadIdx.x, lane = tid & 63, wave = tid >> 6;  // 0..3
    const int l15 = lane & 15, l4 = lane >> 4;
    const int bh = blockIdx.x, b = bh >> 4, h = bh & 15;
    const int yy = blockIdx.y;
    const int qtile = (yy < 8) ? (15 - yy) : (yy - 8);  // pair i with 15-i per CU
    const int q0 = qtile * 128;
    const int qw0 = q0 + wave * 32;          // this wave's 32 q-rows
    const size_t base = (size_t)bh * 2048 * 64;
    const unsigned short* vtb = v_ws + (size_t)bh * 64 * 2048;  // V^T [d][t]
    unsigned short* Pw = &Ps[wave * 32 * LDP];

    // staging: wave = seg; each wave stages both 32-d (resp 32-key) halves of
    // its 16-row K segment and 16-row V^T segment.
    const int seg = wave;
    const unsigned short* kg0[2];
    const unsigned short* vg0[2];
    unsigned short* kl[2][2];
    unsigned short* vl[2][2];
    for (int hf = 0; hf < 2; hf++) {
        kg0[hf] = &k_ws[base + (size_t)(seg * 16 + (lane >> 2)) * 64 + hf * 32 + (lane & 3) * 8];
        vg0[hf] = &vtb[(size_t)(seg * 16 + (lane >> 2)) * 2048 + hf * 32 + (lane & 3) * 8];
        for (int bu = 0; bu < 2; bu++) {
            kl[bu][hf] = &Ks[bu][hf][(seg * 16) * 32];
            vl[bu][hf] = &Vt[bu][hf][(seg * 16) * 32];
        }
    }

    // Q fragments (B-operand: n=q, k=d); q pre-scaled by Dh^-0.5*log2e.
    s16x8 qf[2][2];
    for (int qs = 0; qs < 2; qs++)
        for (int c = 0; c < 2; c++)
            qf[qs][c] = ld8a(&q_ws[base + (size_t)(qw0 + qs * 16 + l15) * 64 + c * 32 + l4 * 8]);

    f32x4 o[2][4];  // O^T tiles [qs][dsub]: row=d, col=q (unnormalized)
    for (int qs = 0; qs < 2; qs++)
        for (int i = 0; i < 4; i++) o[qs][i] = (f32x4){0.f, 0.f, 0.f, 0.f};
    float lsum[2] = {0.f, 0.f};  // per-lane partial denominator per q-subtile

    // prefetch tile 0 into buf 0
    for (int hf = 0; hf < 2; hf++) {
        glds16(kg0[hf], kl[0][hf]);
        glds16(vg0[hf], vl[0][hf]);
    }

    const int kend = q0 + 128;
    for (int k0 = 0; k0 < kend; k0 += 64) {
        const int cur = (k0 >> 6) & 1;
        __syncthreads();  // tile k0 visible; buf cur^1 free (readers done last iter)
        if (k0 + 64 < kend) {  // block-uniform prefetch of next tile
            for (int hf = 0; hf < 2; hf++) {
                glds16(kg0[hf] + (size_t)(k0 + 64) * 64, kl[cur ^ 1][hf]);
                glds16(vg0[hf] + (k0 + 64), vl[cur ^ 1][hf]);
            }
        }

        if (k0 < qw0 + 32) {  // wave-uniform: this wave needs the tile
            // ---- S^T = K*Q^T (A: m=key, k=d); each K frag feeds both qs ----
            f32x4 st[2][4];
            for (int qs = 0; qs < 2; qs++)
                for (int ks = 0; ks < 4; ks++) st[qs][ks] = (f32x4){0.f, 0.f, 0.f, 0.f};
            for (int c = 0; c < 2; c++)
                for (int ks = 0; ks < 4; ks++) {
                    s16x8 kf = ld8a(&Ks[cur][c][(ks * 16 + l15) * 32 + l4 * 8]);
                    st[0][ks] = mfma16(kf, qf[0][c], st[0][ks]);
                    st[1][ks] = mfma16(kf, qf[1][c], st[1][ks]);
                }

            // ---- causal mask (diag only) + exp2 + pack P + accumulate l ----
            if (k0 + 63 > qw0) {  // wave-uniform diagonal check
                for (int qs = 0; qs < 2; qs++) {
                    int qg = qw0 + qs * 16 + l15;
                    for (int ks = 0; ks < 4; ks++)
                        for (int r = 0; r < 4; r++) {
                            int kg = k0 + ks * 16 + l4 * 4 + r;
                            if (kg > qg) st[qs][ks][r] = -1e30f;
                        }
                }
            }
            for (int qs = 0; qs < 2; qs++) {
                float part = 0.f;
                for (int ks = 0; ks < 4; ks++) {
                    float p0 = EXP2(st[qs][ks][0]);
                    float p1 = EXP2(st[qs][ks][1]);
                    float p2 = EXP2(st[qs][ks][2]);
                    float p3 = EXP2(st[qs][ks][3]);
                    part += (p0 + p1) + (p2 + p3);
                    unsigned int u0 = pack2(p0, p1), u1 = pack2(p2, p3);
                    *(uint2*)&Pw[(qs * 16 + l15) * LDP + ks * 16 + l4 * 4] = (uint2){u0, u1};
                }
                lsum[qs] += part;
            }

            // ---- O^T += V^T * P^T; each V frag feeds both qs ----
            s16x8 pf[2][2];
            for (int qs = 0; qs < 2; qs++)
                for (int c = 0; c < 2; c++)
                    pf[qs][c] = ld8(&Pw[(qs * 16 + l15) * LDP + c * 32 + l4 * 8]);
            for (int c = 0; c < 2; c++)
                for (int ds = 0; ds < 4; ds++) {
                    s16x8 vf = ld8a(&Vt[cur][c][(ds * 16 + l15) * 32 + l4 * 8]);
                    o[0][ds] = mfma16(vf, pf[0][c], o[0][ds]);
                    o[1][ds] = mfma16(vf, pf[1][c], o[1][ds]);
                }
        }
    }

    // ---- epilogue: per qs reduce l across l4, normalize, transpose, store ----
    for (int qs = 0; qs < 2; qs++) {
        float t = lsum[qs];
        t += __shfl_xor(t, 16, 64);
        t += __shfl_xor(t, 32, 64);
        float inv = 1.f / t;
        for (int ds = 0; ds < 4; ds++) {
            s16x4 pp;
            for (int r = 0; r < 4; r++) pp[r] = (short)f2bf(o[qs][ds][r] * inv);
            *(s16x4*)&Pw[(qs * 16 + l15) * LDP + ds * 16 + l4 * 4] = pp;  // Ow[q][d]
        }
    }
    for (int qs = 0; qs < 2; qs++) {
        int qr = lane >> 2, qc = lane & 3;
        size_t orow = ((size_t)b * 2048 + q0 + wave * 32 + qs * 16 + qr) * 1024 + h * 64 + qc * 16;
        *(s16x8*)&ao[orow]     = ld8(&Pw[(qs * 16 + qr) * LDP + qc * 16]);
        *(s16x8*)&ao[orow + 8] = ld8(&Pw[(qs * 16 + qr) * LDP + qc * 16 + 8]);
    }
}

// ---------------------------------------------------------------------------
// Output projection: OUT[4096][1024](fp32) = AO(bf16) * Wo(bf16)^T.
// 128(M)x64(N) block tile, 4 waves each 32x64 (acc[2][4]), BK=64.
// Grid 512 blocks -> 2 blocks/CU, 8 waves/CU (cross-block barrier overlap).
// ---------------------------------------------------------------------------
__global__ __launch_bounds__(256) void out_gemm(
        const unsigned short* __restrict__ A, const unsigned short* __restrict__ Bm,
        float* __restrict__ OUT) {
    __shared__ unsigned short As[2][128 * 32];
    __shared__ unsigned short Bs[2][64 * 32];
    const int tid = threadIdx.x, lane = tid & 63, wave = tid >> 6;  // 0..3
    const int l15 = lane & 15, l4 = lane >> 4;
    const int wm = wave * 32;
    const int m0 = blockIdx.y * 128, n0 = blockIdx.x * 64;

    f32x4 acc[2][4];
    for (int i = 0; i < 2; i++)
        for (int j = 0; j < 4; j++) acc[i][j] = (f32x4){0.f, 0.f, 0.f, 0.f};

    // wave stages A rows [wave*32, +32) (2 glds16/half) and B rows [wave*16, +16)
    const unsigned short* aptr = &A[(size_t)(m0 + wave * 32 + (lane >> 2)) * 1024 + (lane & 3) * 8];
    const unsigned short* bptr = &Bm[(size_t)(n0 + wave * 16 + (lane >> 2)) * 1024 + (lane & 3) * 8];

    for (int k0 = 0; k0 < 1024; k0 += 64) {
        __syncthreads();
        for (int c = 0; c < 2; c++) {
            glds16(aptr + k0 + c * 32, &As[c][(wave * 32) * 32]);
            glds16(aptr + k0 + c * 32 + 16 * 1024, &As[c][(wave * 32 + 16) * 32]);
            glds16(bptr + k0 + c * 32, &Bs[c][(wave * 16) * 32]);
        }
        __syncthreads();
        for (int c = 0; c < 2; c++) {
            s16x8 af[2], bf[4];
            for (int mt = 0; mt < 2; mt++) af[mt] = ld8a(&As[c][(wm + mt * 16 + l15) * 32 + l4 * 8]);
            for (int nt = 0; nt < 4; nt++) bf[nt] = ld8a(&Bs[c][(nt * 16 + l15) * 32 + l4 * 8]);
            for (int mt = 0; mt < 2; mt++)
                for (int nt = 0; nt < 4; nt++)
                    acc[mt][nt] = mfma16(af[mt], bf[nt], acc[mt][nt]);
        }
    }

    for (int mt = 0; mt < 2; mt++)
        for (int nt = 0; nt < 4; nt++)
            for (int r = 0; r < 4; r++) {
                int gm = m0 + wm + mt * 16 + l4 * 4 + r;
                int gn = n0 + nt * 16 + l15;
                OUT[(size_t)gm * 1024 + gn] = acc[mt][nt][r];
            }
}

// ---------------------------------------------------------------------------
extern "C" void kernel_launch(void* const* d_in, const int* in_sizes, int n_in,
                              void* d_out, int out_size, void* d_ws, size_t ws_size,
                              hipStream_t stream) {
    (void)in_sizes; (void)n_in; (void)out_size; (void)ws_size;
    const float* x    = (const float*)d_in[0];   // [2,2048,1024]
    const float* Wqkv = (const float*)d_in[1];   // [3072,1024]
    const float* Wout = (const float*)d_in[2];   // [1024,1024]
    float* out = (float*)d_out;                  // [2,2048,1024] fp32

    // 32 MB workspace:
    //   [0,8M)   q_ws [bh][T][64]; reused for Wout-bf16 after attn
    //   [8,16M)  k_ws [bh][T][64]
    //   [16,24M) v_ws TRANSPOSED [bh][64][T]
    //   [24,32M) Xb (bf16 X) during qkv; then attn output AO
    // d_out (16 MB fp32) doubles as scratch for Wqkv-bf16 (6 MB) until
    // out_gemm overwrites every element at the end.
    unsigned short* q_ws = (unsigned short*)d_ws;
    unsigned short* k_ws = q_ws + (size_t)4 * 1024 * 1024;
    unsigned short* v_ws = k_ws + (size_t)4 * 1024 * 1024;
    unsigned short* xb   = v_ws + (size_t)4 * 1024 * 1024;  // 8 MB
    unsigned short* ao   = xb;                              // born in attn, xb dead
    unsigned short* wqb  = (unsigned short*)d_out;          // 6 MB scratch in d_out
    unsigned short* wob  = q_ws;                            // 2 MB, written after attn

    const int n4x = 2 * 2048 * 1024 / 4, n4w = 3072 * 1024 / 4;
    convf2b2<<<(n4x + n4w + 255) / 256, 256, 0, stream>>>(x, xb, n4x, Wqkv, wqb, n4w);
    qkv_gemm<<<dim3(24, 32), 512, 0, stream>>>(xb, wqb, q_ws, k_ws, v_ws);
    attn<<<dim3(32, 16), 256, 0, stream>>>(q_ws, k_ws, v_ws, ao);
    convf2b<<<1024, 256, 0, stream>>>(Wout, wob, 1024 * 1024 / 4);
    out_gemm<<<dim3(16, 32), 256, 0, stream>>>(ao, wob, out);
}

// Round 2
// 170.926 us; speedup vs baseline: 1.0383x; 1.0383x over previous
//
#include <hip/hip_runtime.h>
#include <hip/hip_bf16.h>

typedef __attribute__((ext_vector_type(4))) float f32x4;
typedef __attribute__((ext_vector_type(8))) short s16x8;
typedef __attribute__((ext_vector_type(4))) short s16x4;

#define DEV static __device__ __forceinline__

// fp32 -> bf16 round-to-nearest-even
DEV unsigned short f2bf(float f) {
    unsigned int u = __builtin_bit_cast(unsigned int, f);
    u += 0x7fffu + ((u >> 16) & 1u);
    return (unsigned short)(u >> 16);
}

#if __has_builtin(__builtin_amdgcn_exp2f)
#define EXP2(x) __builtin_amdgcn_exp2f(x)
#else
#define EXP2(x) exp2f(x)
#endif

// pack two fp32 -> two truncated bf16 in one dword (low short = a, high = b)
DEV unsigned int pack2(float a, float b) {
#if __has_builtin(__builtin_amdgcn_perm)
    return __builtin_amdgcn_perm(__builtin_bit_cast(unsigned int, b),
                                 __builtin_bit_cast(unsigned int, a), 0x07060302u);
#else
    return (__builtin_bit_cast(unsigned int, a) >> 16) |
           (__builtin_bit_cast(unsigned int, b) & 0xffff0000u);
#endif
}

// 8 bf16 from LDS via two 8B reads (padded strides: only 8B alignment)
DEV s16x8 ld8(const unsigned short* p) {
    s16x4 lo = *(const s16x4*)(p);
    s16x4 hi = *(const s16x4*)(p + 4);
    return __builtin_shufflevector(lo, hi, 0, 1, 2, 3, 4, 5, 6, 7);
}
// 16B-aligned single b128 read
DEV s16x8 ld8a(const unsigned short* p) { return *(const s16x8*)p; }

DEV f32x4 mfma16(s16x8 a, s16x8 b, f32x4 c) {
    return __builtin_amdgcn_mfma_f32_16x16x32_bf16(a, b, c, 0, 0, 0);
}

// async global->LDS, 16B per lane; lds dest = wave-uniform base + lane*16
DEV void glds16(const unsigned short* g, unsigned short* l) {
    __builtin_amdgcn_global_load_lds(
        (const __attribute__((address_space(1))) unsigned int*)g,
        (__attribute__((address_space(3))) unsigned int*)l, 16, 0, 0);
}

struct QS1 { static constexpr int v = 1; };
struct QS2 { static constexpr int v = 2; };

// ---------------------------------------------------------------------------
// fp32 -> bf16 bulk cast over two disjoint regions (one launch)
// ---------------------------------------------------------------------------
__global__ __launch_bounds__(256) void convf2b2(
        const float* __restrict__ s0, unsigned short* __restrict__ d0, int n40,
        const float* __restrict__ s1, unsigned short* __restrict__ d1, int n41) {
    int i = blockIdx.x * 256 + threadIdx.x;
    if (i < n40) {
        float4 v = ((const float4*)s0)[i];
        s16x4 o = {(short)f2bf(v.x), (short)f2bf(v.y), (short)f2bf(v.z), (short)f2bf(v.w)};
        ((s16x4*)d0)[i] = o;
    } else if (i - n40 < n41) {
        int j = i - n40;
        float4 v = ((const float4*)s1)[j];
        s16x4 o = {(short)f2bf(v.x), (short)f2bf(v.y), (short)f2bf(v.z), (short)f2bf(v.w)};
        ((s16x4*)d1)[j] = o;
    }
}

__global__ __launch_bounds__(256) void convf2b(const float* __restrict__ s,
                                               unsigned short* __restrict__ d, int n4) {
    int i = blockIdx.x * 256 + threadIdx.x;
    if (i < n4) {
        float4 v = ((const float4*)s)[i];
        s16x4 o = {(short)f2bf(v.x), (short)f2bf(v.y), (short)f2bf(v.z), (short)f2bf(v.w)};
        ((s16x4*)d)[i] = o;
    }
}

// ---------------------------------------------------------------------------
// QKV projection: C[4096][3072] = Xb[4096][1024](bf16) * Wq[3072][1024](bf16)^T
// 512 threads = 8 waves, wave tile 32x64 (acc[2][4]). 128x128 block, BK=64.
// ---------------------------------------------------------------------------
__global__ __launch_bounds__(512) void qkv_gemm(
        const unsigned short* __restrict__ Xb, const unsigned short* __restrict__ Wq,
        unsigned short* __restrict__ q_ws, unsigned short* __restrict__ k_ws,
        unsigned short* __restrict__ v_ws) {
    __shared__ unsigned short As[2][128 * 32];
    __shared__ unsigned short Bs[2][128 * 32];
    const int tid = threadIdx.x, lane = tid & 63, wave = tid >> 6;  // 0..7
    const int l15 = lane & 15, l4 = lane >> 4;
    const int wm = (wave >> 1) * 32, wn = (wave & 1) * 64;
    const int m0 = blockIdx.y * 128, n0 = blockIdx.x * 128;

    f32x4 acc[2][4];
    for (int i = 0; i < 2; i++)
        for (int j = 0; j < 4; j++) acc[i][j] = (f32x4){0.f, 0.f, 0.f, 0.f};

    const unsigned short* aptr = &Xb[(size_t)(m0 + wave * 16 + (lane >> 2)) * 1024 + (lane & 3) * 8];
    const unsigned short* bptr = &Wq[(size_t)(n0 + wave * 16 + (lane >> 2)) * 1024 + (lane & 3) * 8];

    for (int k0 = 0; k0 < 1024; k0 += 64) {
        __syncthreads();
        for (int c = 0; c < 2; c++) {
            glds16(aptr + k0 + c * 32, &As[c][(wave * 16) * 32]);
            glds16(bptr + k0 + c * 32, &Bs[c][(wave * 16) * 32]);
        }
        __syncthreads();
        for (int c = 0; c < 2; c++) {
            s16x8 af[2], bf[4];
            for (int mt = 0; mt < 2; mt++) af[mt] = ld8a(&As[c][(wm + mt * 16 + l15) * 32 + l4 * 8]);
            for (int nt = 0; nt < 4; nt++) bf[nt] = ld8a(&Bs[c][(wn + nt * 16 + l15) * 32 + l4 * 8]);
            for (int mt = 0; mt < 2; mt++)
                for (int nt = 0; nt < 4; nt++)
                    acc[mt][nt] = mfma16(af[mt], bf[nt], acc[mt][nt]);
        }
    }

    // epilogue (C/D layout: row=(lane>>4)*4+reg, col=lane&15)
    const int gnb = n0 + wn;  // 64-aligned -> one (which, head) per wave
    const int which = gnb >> 10, h = (gnb >> 6) & 15;
    const int bidx = m0 >> 11, tb = m0 & 2047;
    if (which == 2) {
        // V transposed: v_ws[bh][dh][t], 4 consecutive t per lane -> 8B store
        unsigned short* dst = v_ws + (size_t)(bidx * 16 + h) * 64 * 2048;
        for (int mt = 0; mt < 2; mt++) {
            int t = tb + wm + mt * 16 + l4 * 4;
            for (int nt = 0; nt < 4; nt++) {
                int dh = nt * 16 + l15;
                s16x4 pp;
                for (int r = 0; r < 4; r++) pp[r] = (short)f2bf(acc[mt][nt][r]);
                *(s16x4*)&dst[(size_t)dh * 2048 + t] = pp;
            }
        }
    } else {
        unsigned short* dst = ((which == 0) ? q_ws : k_ws) + (size_t)(bidx * 16 + h) * 2048 * 64;
        // q folded scale: Dh^-0.5 * log2(e) so attention uses raw exp2
        const float sc = (which == 0) ? 0.18033688f : 1.0f;
        for (int mt = 0; mt < 2; mt++) {
            int t0 = tb + wm + mt * 16 + l4 * 4;
            for (int nt = 0; nt < 4; nt++) {
                int dh = nt * 16 + l15;
                for (int r = 0; r < 4; r++)
                    dst[(size_t)(t0 + r) * 64 + dh] = f2bf(acc[mt][nt][r] * sc);
            }
        }
    }
}

// ---------------------------------------------------------------------------
// Causal flash attention v9: concurrent causal fold.
// Block (4 waves, 256 thr) handles chunk p (64 q) + chunk 31-p (64 q) at 64-row
// granularity. Per wave: qs0 = 16 rows of HIGH chunk (active all k-tiles),
// qs1 = 16 rows of LOW chunk (active first p+1 tiles). Loop = 32-p tiles;
// active wave-tiles = 33 uniform for every wave. Block-ID encoding:
//   id = (bh&7) + 8*(q + 16*g), bh = (bh&7)+8*g, p = g<2 ? q : 15-q
// -> co-resident pair (c, c+256) has complementary p (total 49 iters/CU,
//    >=70% dual-block overlap; v8 worst case was 2-vs-32 iters -> solo CU)
// -> XCD = bh%8 keeps K/V L2-resident (2 MB/XCD).
// K/V LDS reads swizzled (slot ^= (row>>1)&3, pre-swizzled glds source) to
// kill the 8-way ds_read_b128 bank conflict. setprio(1) around MFMA (T5).
// ---------------------------------------------------------------------------
__global__ __launch_bounds__(256) void attn(
        const unsigned short* __restrict__ q_ws, const unsigned short* __restrict__ k_ws,
        const unsigned short* __restrict__ v_ws, unsigned short* __restrict__ ao) {
    constexpr int LDP = 68;  // dword stride 34 -> cheap 2-way
    __shared__ unsigned short Ks[2][2][64 * 32];  // [buf][d-half][key][32 d]
    __shared__ unsigned short Vt[2][2][64 * 32];  // [buf][key-half][d][32 key]
    __shared__ unsigned short Ps[4 * 32 * LDP];   // per-wave P rows (2 qs x 16)
    const int tid = threadIdx.x, lane = tid & 63, wave = tid >> 6;  // 0..3
    const int l15 = lane & 15, l4 = lane >> 4;
    const int xf = (l15 >> 1) & 3;  // K/V read-slot swizzle factor

    // fold decode
    const int id = blockIdx.x;
    const int bh8 = id & 7, rest = id >> 3;
    const int qq = rest & 15, g = rest >> 4;
    const int bh = bh8 + 8 * g, b = bh >> 4, h = bh & 15;
    const int p = (g < 2) ? qq : 15 - qq;
    const int rb[2] = {(31 - p) * 64 + wave * 16,   // qs0: high chunk rows
                       p * 64 + wave * 16};         // qs1: low chunk rows
    const int kend = (32 - p) * 64;

    const size_t base = (size_t)bh * 2048 * 64;
    const unsigned short* vtb = v_ws + (size_t)bh * 64 * 2048;  // V^T [d][t]
    unsigned short* Pw = &Ps[wave * 32 * LDP];

    // staging: wave = seg stages 16 rows of K and of V^T, both 32-wide halves.
    // Source column pre-swizzled so linear LDS dest + swizzled read match.
    const int seg = wave;
    const int srow = lane >> 2;
    const int scol = ((lane & 3) ^ ((lane >> 3) & 3)) * 8;  // shorts
    const unsigned short* kg0[2];
    const unsigned short* vg0[2];
    unsigned short* kl[2][2];
    unsigned short* vl[2][2];
    for (int hf = 0; hf < 2; hf++) {
        kg0[hf] = &k_ws[base + (size_t)(seg * 16 + srow) * 64 + hf * 32 + scol];
        vg0[hf] = &vtb[(size_t)(seg * 16 + srow) * 2048 + hf * 32 + scol];
        for (int bu = 0; bu < 2; bu++) {
            kl[bu][hf] = &Ks[bu][hf][(seg * 16) * 32];
            vl[bu][hf] = &Vt[bu][hf][(seg * 16) * 32];
        }
    }

    // Q fragments (B-operand: n=q, k=d); q pre-scaled by Dh^-0.5*log2e.
    s16x8 qf[2][2];
    for (int qs = 0; qs < 2; qs++)
        for (int c = 0; c < 2; c++)
            qf[qs][c] = ld8a(&q_ws[base + (size_t)(rb[qs] + l15) * 64 + c * 32 + l4 * 8]);

    f32x4 o[2][4];  // O^T tiles [qs][dsub]: row=d, col=q (unnormalized)
    for (int qs = 0; qs < 2; qs++)
        for (int i = 0; i < 4; i++) o[qs][i] = (f32x4){0.f, 0.f, 0.f, 0.f};
    float lsum[2] = {0.f, 0.f};

    // prefetch tile 0 into buf 0
    for (int hf = 0; hf < 2; hf++) {
        glds16(kg0[hf], kl[0][hf]);
        glds16(vg0[hf], vl[0][hf]);
    }

    for (int k0 = 0; k0 < kend; k0 += 64) {
        const int cur = (k0 >> 6) & 1;
        __syncthreads();  // tile k0 visible; buf cur^1 free
        if (k0 + 64 < kend) {  // block-uniform prefetch of next tile
            for (int hf = 0; hf < 2; hf++) {
                glds16(kg0[hf] + (size_t)(k0 + 64) * 64, kl[cur ^ 1][hf]);
                glds16(vg0[hf] + (k0 + 64), vl[cur ^ 1][hf]);
            }
        }

        auto tile = [&](auto tag) {
            constexpr int NQS = decltype(tag)::v;
            // ---- S^T = K*Q^T (A: m=key, k=d); K frag feeds NQS q-subtiles ----
            f32x4 st[NQS][4];
            for (int qs = 0; qs < NQS; qs++)
                for (int ks = 0; ks < 4; ks++) st[qs][ks] = (f32x4){0.f, 0.f, 0.f, 0.f};
            __builtin_amdgcn_s_setprio(1);
            for (int c = 0; c < 2; c++)
                for (int ks = 0; ks < 4; ks++) {
                    s16x8 kf = ld8a(&Ks[cur][c][(ks * 16 + l15) * 32 + (l4 ^ xf) * 8]);
                    for (int qs = 0; qs < NQS; qs++)
                        st[qs][ks] = mfma16(kf, qf[qs][c], st[qs][ks]);
                }
            __builtin_amdgcn_s_setprio(0);

            // ---- causal mask (diag only) + exp2 + pack P + accumulate l ----
            for (int qs = 0; qs < NQS; qs++)
                if (k0 + 63 > rb[qs]) {  // wave-uniform diagonal check
                    int qg = rb[qs] + l15;
                    for (int ks = 0; ks < 4; ks++)
                        for (int r = 0; r < 4; r++) {
                            int kg = k0 + ks * 16 + l4 * 4 + r;
                            if (kg > qg) st[qs][ks][r] = -1e30f;
                        }
                }
            for (int qs = 0; qs < NQS; qs++) {
                float part = 0.f;
                for (int ks = 0; ks < 4; ks++) {
                    float p0 = EXP2(st[qs][ks][0]);
                    float p1 = EXP2(st[qs][ks][1]);
                    float p2 = EXP2(st[qs][ks][2]);
                    float p3 = EXP2(st[qs][ks][3]);
                    part += (p0 + p1) + (p2 + p3);
                    unsigned int u0 = pack2(p0, p1), u1 = pack2(p2, p3);
                    *(uint2*)&Pw[(qs * 16 + l15) * LDP + ks * 16 + l4 * 4] = (uint2){u0, u1};
                }
                lsum[qs] += part;
            }

            // ---- O^T += V^T * P^T; V frag feeds NQS q-subtiles ----
            s16x8 pf[NQS][2];
            for (int qs = 0; qs < NQS; qs++)
                for (int c = 0; c < 2; c++)
                    pf[qs][c] = ld8(&Pw[(qs * 16 + l15) * LDP + c * 32 + l4 * 8]);
            __builtin_amdgcn_s_setprio(1);
            for (int c = 0; c < 2; c++)
                for (int ds = 0; ds < 4; ds++) {
                    s16x8 vf = ld8a(&Vt[cur][c][(ds * 16 + l15) * 32 + (l4 ^ xf) * 8]);
                    for (int qs = 0; qs < NQS; qs++)
                        o[qs][ds] = mfma16(vf, pf[qs][c], o[qs][ds]);
                }
            __builtin_amdgcn_s_setprio(0);
        };

        if (k0 < rb[1] + 16) tile(QS2{});  // low chunk still active (wave-uniform)
        else                 tile(QS1{});  // high chunk only
    }

    // ---- epilogue: per qs reduce l across l4, normalize, transpose, store ----
    for (int qs = 0; qs < 2; qs++) {
        float t = lsum[qs];
        t += __shfl_xor(t, 16, 64);
        t += __shfl_xor(t, 32, 64);
        float inv = 1.f / t;
        for (int ds = 0; ds < 4; ds++) {
            s16x4 pp;
            for (int r = 0; r < 4; r++) pp[r] = (short)f2bf(o[qs][ds][r] * inv);
            *(s16x4*)&Pw[(qs * 16 + l15) * LDP + ds * 16 + l4 * 4] = pp;  // Ow[q][d]
        }
    }
    for (int qs = 0; qs < 2; qs++) {
        int qr = lane >> 2, qc = lane & 3;
        size_t orow = ((size_t)b * 2048 + rb[qs] + qr) * 1024 + h * 64 + qc * 16;
        *(s16x8*)&ao[orow]     = ld8(&Pw[(qs * 16 + qr) * LDP + qc * 16]);
        *(s16x8*)&ao[orow + 8] = ld8(&Pw[(qs * 16 + qr) * LDP + qc * 16 + 8]);
    }
}

// ---------------------------------------------------------------------------
// Output projection: OUT[4096][1024](fp32) = AO(bf16) * Wo(bf16)^T.
// ---------------------------------------------------------------------------
__global__ __launch_bounds__(256) void out_gemm(
        const unsigned short* __restrict__ A, const unsigned short* __restrict__ Bm,
        float* __restrict__ OUT) {
    __shared__ unsigned short As[2][128 * 32];
    __shared__ unsigned short Bs[2][64 * 32];
    const int tid = threadIdx.x, lane = tid & 63, wave = tid >> 6;  // 0..3
    const int l15 = lane & 15, l4 = lane >> 4;
    const int wm = wave * 32;
    const int m0 = blockIdx.y * 128, n0 = blockIdx.x * 64;

    f32x4 acc[2][4];
    for (int i = 0; i < 2; i++)
        for (int j = 0; j < 4; j++) acc[i][j] = (f32x4){0.f, 0.f, 0.f, 0.f};

    const unsigned short* aptr = &A[(size_t)(m0 + wave * 32 + (lane >> 2)) * 1024 + (lane & 3) * 8];
    const unsigned short* bptr = &Bm[(size_t)(n0 + wave * 16 + (lane >> 2)) * 1024 + (lane & 3) * 8];

    for (int k0 = 0; k0 < 1024; k0 += 64) {
        __syncthreads();
        for (int c = 0; c < 2; c++) {
            glds16(aptr + k0 + c * 32, &As[c][(wave * 32) * 32]);
            glds16(aptr + k0 + c * 32 + 16 * 1024, &As[c][(wave * 32 + 16) * 32]);
            glds16(bptr + k0 + c * 32, &Bs[c][(wave * 16) * 32]);
        }
        __syncthreads();
        for (int c = 0; c < 2; c++) {
            s16x8 af[2], bf[4];
            for (int mt = 0; mt < 2; mt++) af[mt] = ld8a(&As[c][(wm + mt * 16 + l15) * 32 + l4 * 8]);
            for (int nt = 0; nt < 4; nt++) bf[nt] = ld8a(&Bs[c][(nt * 16 + l15) * 32 + l4 * 8]);
            for (int mt = 0; mt < 2; mt++)
                for (int nt = 0; nt < 4; nt++)
                    acc[mt][nt] = mfma16(af[mt], bf[nt], acc[mt][nt]);
        }
    }

    for (int mt = 0; mt < 2; mt++)
        for (int nt = 0; nt < 4; nt++)
            for (int r = 0; r < 4; r++) {
                int gm = m0 + wm + mt * 16 + l4 * 4 + r;
                int gn = n0 + nt * 16 + l15;
                OUT[(size_t)gm * 1024 + gn] = acc[mt][nt][r];
            }
}

// ---------------------------------------------------------------------------
extern "C" void kernel_launch(void* const* d_in, const int* in_sizes, int n_in,
                              void* d_out, int out_size, void* d_ws, size_t ws_size,
                              hipStream_t stream) {
    (void)in_sizes; (void)n_in; (void)out_size; (void)ws_size;
    const float* x    = (const float*)d_in[0];   // [2,2048,1024]
    const float* Wqkv = (const float*)d_in[1];   // [3072,1024]
    const float* Wout = (const float*)d_in[2];   // [1024,1024]
    float* out = (float*)d_out;                  // [2,2048,1024] fp32

    unsigned short* q_ws = (unsigned short*)d_ws;
    unsigned short* k_ws = q_ws + (size_t)4 * 1024 * 1024;
    unsigned short* v_ws = k_ws + (size_t)4 * 1024 * 1024;
    unsigned short* xb   = v_ws + (size_t)4 * 1024 * 1024;  // 8 MB
    unsigned short* ao   = xb;                              // born in attn, xb dead
    unsigned short* wqb  = (unsigned short*)d_out;          // 6 MB scratch in d_out
    unsigned short* wob  = q_ws;                            // 2 MB, written after attn

    const int n4x = 2 * 2048 * 1024 / 4, n4w = 3072 * 1024 / 4;
    convf2b2<<<(n4x + n4w + 255) / 256, 256, 0, stream>>>(x, xb, n4x, Wqkv, wqb, n4w);
    qkv_gemm<<<dim3(24, 32), 512, 0, stream>>>(xb, wqb, q_ws, k_ws, v_ws);
    attn<<<dim3(512), 256, 0, stream>>>(q_ws, k_ws, v_ws, ao);
    convf2b<<<1024, 256, 0, stream>>>(Wout, wob, 1024 * 1024 / 4);
    out_gemm<<<dim3(16, 32), 256, 0, stream>>>(ao, wob, out);
}

// Round 3
// 164.980 us; speedup vs baseline: 1.0757x; 1.0360x over previous
//
#include <hip/hip_runtime.h>
#include <hip/hip_bf16.h>

typedef __attribute__((ext_vector_type(4))) float f32x4;
typedef __attribute__((ext_vector_type(8))) short s16x8;
typedef __attribute__((ext_vector_type(4))) short s16x4;

#define DEV static __device__ __forceinline__

// fp32 -> bf16 round-to-nearest-even
DEV unsigned short f2bf(float f) {
    unsigned int u = __builtin_bit_cast(unsigned int, f);
    u += 0x7fffu + ((u >> 16) & 1u);
    return (unsigned short)(u >> 16);
}

#if __has_builtin(__builtin_amdgcn_exp2f)
#define EXP2(x) __builtin_amdgcn_exp2f(x)
#else
#define EXP2(x) exp2f(x)
#endif

// pack two fp32 -> two truncated bf16 in one dword (low short = a, high = b)
DEV unsigned int pack2(float a, float b) {
#if __has_builtin(__builtin_amdgcn_perm)
    return __builtin_amdgcn_perm(__builtin_bit_cast(unsigned int, b),
                                 __builtin_bit_cast(unsigned int, a), 0x07060302u);
#else
    return (__builtin_bit_cast(unsigned int, a) >> 16) |
           (__builtin_bit_cast(unsigned int, b) & 0xffff0000u);
#endif
}

// 8 bf16 from LDS via two 8B reads (padded strides: only 8B alignment)
DEV s16x8 ld8(const unsigned short* p) {
    s16x4 lo = *(const s16x4*)(p);
    s16x4 hi = *(const s16x4*)(p + 4);
    return __builtin_shufflevector(lo, hi, 0, 1, 2, 3, 4, 5, 6, 7);
}
// 16B-aligned single b128 read
DEV s16x8 ld8a(const unsigned short* p) { return *(const s16x8*)p; }

DEV f32x4 mfma16(s16x8 a, s16x8 b, f32x4 c) {
    return __builtin_amdgcn_mfma_f32_16x16x32_bf16(a, b, c, 0, 0, 0);
}

// async global->LDS, 16B per lane; lds dest = wave-uniform base + lane*16
DEV void glds16(const unsigned short* g, unsigned short* l) {
    __builtin_amdgcn_global_load_lds(
        (const __attribute__((address_space(1))) unsigned int*)g,
        (__attribute__((address_space(3))) unsigned int*)l, 16, 0, 0);
}

// ---------------------------------------------------------------------------
// fp32 -> bf16 bulk cast over two disjoint regions (one launch)
// ---------------------------------------------------------------------------
__global__ __launch_bounds__(256) void convf2b2(
        const float* __restrict__ s0, unsigned short* __restrict__ d0, int n40,
        const float* __restrict__ s1, unsigned short* __restrict__ d1, int n41) {
    int i = blockIdx.x * 256 + threadIdx.x;
    if (i < n40) {
        float4 v = ((const float4*)s0)[i];
        s16x4 o = {(short)f2bf(v.x), (short)f2bf(v.y), (short)f2bf(v.z), (short)f2bf(v.w)};
        ((s16x4*)d0)[i] = o;
    } else if (i - n40 < n41) {
        int j = i - n40;
        float4 v = ((const float4*)s1)[j];
        s16x4 o = {(short)f2bf(v.x), (short)f2bf(v.y), (short)f2bf(v.z), (short)f2bf(v.w)};
        ((s16x4*)d1)[j] = o;
    }
}

__global__ __launch_bounds__(256) void convf2b(const float* __restrict__ s,
                                               unsigned short* __restrict__ d, int n4) {
    int i = blockIdx.x * 256 + threadIdx.x;
    if (i < n4) {
        float4 v = ((const float4*)s)[i];
        s16x4 o = {(short)f2bf(v.x), (short)f2bf(v.y), (short)f2bf(v.z), (short)f2bf(v.w)};
        ((s16x4*)d)[i] = o;
    }
}

// ---------------------------------------------------------------------------
// QKV projection: C[4096][3072] = Xb[4096][1024](bf16) * Wq[3072][1024](bf16)^T
// 512 threads = 8 waves, wave tile 32x64 (acc[2][4]). 128x128 block, BK=64.
// ---------------------------------------------------------------------------
__global__ __launch_bounds__(512) void qkv_gemm(
        const unsigned short* __restrict__ Xb, const unsigned short* __restrict__ Wq,
        unsigned short* __restrict__ q_ws, unsigned short* __restrict__ k_ws,
        unsigned short* __restrict__ v_ws) {
    __shared__ unsigned short As[2][128 * 32];
    __shared__ unsigned short Bs[2][128 * 32];
    const int tid = threadIdx.x, lane = tid & 63, wave = tid >> 6;  // 0..7
    const int l15 = lane & 15, l4 = lane >> 4;
    const int wm = (wave >> 1) * 32, wn = (wave & 1) * 64;
    const int m0 = blockIdx.y * 128, n0 = blockIdx.x * 128;

    f32x4 acc[2][4];
    for (int i = 0; i < 2; i++)
        for (int j = 0; j < 4; j++) acc[i][j] = (f32x4){0.f, 0.f, 0.f, 0.f};

    const unsigned short* aptr = &Xb[(size_t)(m0 + wave * 16 + (lane >> 2)) * 1024 + (lane & 3) * 8];
    const unsigned short* bptr = &Wq[(size_t)(n0 + wave * 16 + (lane >> 2)) * 1024 + (lane & 3) * 8];

    for (int k0 = 0; k0 < 1024; k0 += 64) {
        __syncthreads();
        for (int c = 0; c < 2; c++) {
            glds16(aptr + k0 + c * 32, &As[c][(wave * 16) * 32]);
            glds16(bptr + k0 + c * 32, &Bs[c][(wave * 16) * 32]);
        }
        __syncthreads();
        for (int c = 0; c < 2; c++) {
            s16x8 af[2], bf[4];
            for (int mt = 0; mt < 2; mt++) af[mt] = ld8a(&As[c][(wm + mt * 16 + l15) * 32 + l4 * 8]);
            for (int nt = 0; nt < 4; nt++) bf[nt] = ld8a(&Bs[c][(wn + nt * 16 + l15) * 32 + l4 * 8]);
            for (int mt = 0; mt < 2; mt++)
                for (int nt = 0; nt < 4; nt++)
                    acc[mt][nt] = mfma16(af[mt], bf[nt], acc[mt][nt]);
        }
    }

    // epilogue (C/D layout: row=(lane>>4)*4+reg, col=lane&15)
    const int gnb = n0 + wn;  // 64-aligned -> one (which, head) per wave
    const int which = gnb >> 10, h = (gnb >> 6) & 15;
    const int bidx = m0 >> 11, tb = m0 & 2047;
    if (which == 2) {
        // V transposed: v_ws[bh][dh][t], 4 consecutive t per lane -> 8B store
        unsigned short* dst = v_ws + (size_t)(bidx * 16 + h) * 64 * 2048;
        for (int mt = 0; mt < 2; mt++) {
            int t = tb + wm + mt * 16 + l4 * 4;
            for (int nt = 0; nt < 4; nt++) {
                int dh = nt * 16 + l15;
                s16x4 pp;
                for (int r = 0; r < 4; r++) pp[r] = (short)f2bf(acc[mt][nt][r]);
                *(s16x4*)&dst[(size_t)dh * 2048 + t] = pp;
            }
        }
    } else {
        unsigned short* dst = ((which == 0) ? q_ws : k_ws) + (size_t)(bidx * 16 + h) * 2048 * 64;
        // q folded scale: Dh^-0.5 * log2(e) so attention uses raw exp2
        const float sc = (which == 0) ? 0.18033688f : 1.0f;
        for (int mt = 0; mt < 2; mt++) {
            int t0 = tb + wm + mt * 16 + l4 * 4;
            for (int nt = 0; nt < 4; nt++) {
                int dh = nt * 16 + l15;
                for (int r = 0; r < 4; r++)
                    dst[(size_t)(t0 + r) * 64 + dh] = f2bf(acc[mt][nt][r] * sc);
            }
        }
    }
}

// ---------------------------------------------------------------------------
// Causal flash attention v10: 8 waves x 16 q-rows, cross-wave causal fold,
// 3-buffer 2-ahead prefetch with counted vmcnt + raw s_barrier.
//   waves 0-3: high chunk (31-p)*64 rows  (active all nt = 32-p rounds)
//   waves 4-7: low  chunk p*64 rows       (active first p+1 rounds)
// Grid 512 blocks x 512 thr = 16 waves/CU = 4/SIMD. Co-resident pair
// (c, c+256) has complementary p. Per round each wave issues exactly 2
// global_load_lds (tile r+2), waits vmcnt(2) (vmcnt(0) on last round) before
// the barrier, and issues AFTER the barrier (buf (r-1)%3 provably free).
// Each load gets ~2 compute rounds to land -> HBM/L3 latency covered.
// ---------------------------------------------------------------------------
__global__ __launch_bounds__(512, 4) void attn(
        const unsigned short* __restrict__ q_ws, const unsigned short* __restrict__ k_ws,
        const unsigned short* __restrict__ v_ws, unsigned short* __restrict__ ao) {
    constexpr int LDP = 68;  // dword stride 34 -> cheap 2-way
    __shared__ unsigned short Ks[3][2][64 * 32];  // [buf][d-half][key][32 d]
    __shared__ unsigned short Vt[3][2][64 * 32];  // [buf][key-half][d][32 key]
    __shared__ unsigned short Ps[8 * 16 * LDP];   // per-wave P / epilogue O
    const int tid = threadIdx.x, lane = tid & 63, wave = tid >> 6;  // 0..7
    const int l15 = lane & 15, l4 = lane >> 4;
    const int xf = (l15 >> 1) & 3;  // K/V read-slot swizzle (matched on glds src)

    // fold decode: id = (bh&7) + 8*(qq + 16*g), bh = (bh&7)+8g, p = g<2?qq:15-qq
    const int id = blockIdx.x;
    const int bh8 = id & 7, rest = id >> 3;
    const int qq = rest & 15, g = rest >> 4;
    const int bh = bh8 + 8 * g, b = bh >> 4, h = bh & 15;
    const int p = (g < 2) ? qq : 15 - qq;
    const int qrow = ((wave < 4) ? (31 - p) : p) * 64 + (wave & 3) * 16;
    const int nt = 32 - p;  // k-tiles this block processes

    const size_t base = (size_t)bh * 2048 * 64;
    const unsigned short* vtb = v_ws + (size_t)bh * 64 * 2048;  // V^T [d][t]
    unsigned short* Pw = &Ps[wave * 16 * LDP];

    // staging: wave stages K rows [seg*16,+16) half hf, and same V^T segment.
    // glds dest is linear (base+lane*16); source col pre-swizzled to match
    // the (l4^xf) read swizzle.
    const int seg = wave >> 1, hf = wave & 1;
    const int srow = lane >> 2;
    const int scol = ((lane & 3) ^ ((lane >> 3) & 3)) * 8;  // shorts
    const unsigned short* kg = &k_ws[base + (size_t)(seg * 16 + srow) * 64 + hf * 32 + scol];
    const unsigned short* vg = &vtb[(size_t)(seg * 16 + srow) * 2048 + hf * 32 + scol];
    unsigned short* kld = &Ks[0][hf][(seg * 16) * 32];  // + buf*4096
    unsigned short* vld = &Vt[0][hf][(seg * 16) * 32];
    const unsigned short* krd = &Ks[0][0][0];           // + cur*4096 + c*2048
    const unsigned short* vrd = &Vt[0][0][0];

    // Q fragments (B-operand: n=q, k=d); q pre-scaled by Dh^-0.5*log2e.
    s16x8 qf[2];
    for (int c = 0; c < 2; c++)
        qf[c] = ld8a(&q_ws[base + (size_t)(qrow + l15) * 64 + c * 32 + l4 * 8]);
    asm volatile("s_waitcnt vmcnt(0)" ::: "memory");  // clean slate for manual counts

    f32x4 o[4];  // O^T tiles [dsub]: row=d, col=q (unnormalized)
    for (int i = 0; i < 4; i++) o[i] = (f32x4){0.f, 0.f, 0.f, 0.f};
    float lsum = 0.f;

    // prologue: prefetch tiles 0 and 1 (nt >= 17 always)
    glds16(kg, kld);
    glds16(vg, vld);
    glds16(kg + 4096, kld + 4096);
    glds16(vg + 64, vld + 4096);

    int cur = 0;
    for (int r = 0; r < nt; ++r) {
        if (r + 1 < nt) asm volatile("s_waitcnt vmcnt(2)" ::: "memory");
        else            asm volatile("s_waitcnt vmcnt(0)" ::: "memory");
        __builtin_amdgcn_s_barrier();  // tile r visible; buf (r-1)%3 free
        if (r + 2 < nt) {
            const int nb = (cur == 0) ? 2 : cur - 1;  // (r+2)%3
            glds16(kg + (size_t)(r + 2) * 4096, kld + nb * 4096);
            glds16(vg + (r + 2) * 64,           vld + nb * 4096);
        }
        const int k0 = r * 64;
        if (k0 < qrow + 16) {  // wave-uniform: this wave still needs keys
            const unsigned short* kb = krd + cur * 4096;
            const unsigned short* vb = vrd + cur * 4096;
            // ---- S^T = K*Q^T (A: m=key, k=d) ----
            f32x4 st[4];
            for (int ks = 0; ks < 4; ks++) st[ks] = (f32x4){0.f, 0.f, 0.f, 0.f};
            __builtin_amdgcn_s_setprio(1);
            for (int c = 0; c < 2; c++)
                for (int ks = 0; ks < 4; ks++) {
                    s16x8 kf = ld8a(&kb[c * 2048 + (ks * 16 + l15) * 32 + (l4 ^ xf) * 8]);
                    st[ks] = mfma16(kf, qf[c], st[ks]);
                }
            __builtin_amdgcn_s_setprio(0);

            // ---- causal mask (diag tiles only) + exp2 + pack P + l ----
            if (k0 + 63 > qrow) {  // wave-uniform diagonal check
                int qg = qrow + l15;
                for (int ks = 0; ks < 4; ks++)
                    for (int rr = 0; rr < 4; rr++) {
                        int kgi = k0 + ks * 16 + l4 * 4 + rr;
                        if (kgi > qg) st[ks][rr] = -1e30f;
                    }
            }
            float part = 0.f;
            for (int ks = 0; ks < 4; ks++) {
                float p0 = EXP2(st[ks][0]);
                float p1 = EXP2(st[ks][1]);
                float p2 = EXP2(st[ks][2]);
                float p3 = EXP2(st[ks][3]);
                part += (p0 + p1) + (p2 + p3);
                unsigned int u0 = pack2(p0, p1), u1 = pack2(p2, p3);
                *(uint2*)&Pw[l15 * LDP + ks * 16 + l4 * 4] = (uint2){u0, u1};
            }
            lsum += part;

            // ---- O^T += V^T * P^T ----
            s16x8 pf[2];
            for (int c = 0; c < 2; c++)
                pf[c] = ld8(&Pw[l15 * LDP + c * 32 + l4 * 8]);
            __builtin_amdgcn_s_setprio(1);
            for (int c = 0; c < 2; c++)
                for (int ds = 0; ds < 4; ds++) {
                    s16x8 vf = ld8a(&vb[c * 2048 + (ds * 16 + l15) * 32 + (l4 ^ xf) * 8]);
                    o[ds] = mfma16(vf, pf[c], o[ds]);
                }
            __builtin_amdgcn_s_setprio(0);
        }
        cur = (cur == 2) ? 0 : cur + 1;
    }

    // ---- epilogue: reduce l across l4, normalize, transpose, store ----
    float t = lsum;
    t += __shfl_xor(t, 16, 64);
    t += __shfl_xor(t, 32, 64);
    float inv = 1.f / t;
    for (int ds = 0; ds < 4; ds++) {
        s16x4 pp;
        for (int r = 0; r < 4; r++) pp[r] = (short)f2bf(o[ds][r] * inv);
        *(s16x4*)&Pw[l15 * LDP + ds * 16 + l4 * 4] = pp;  // Ow[q][d]
    }
    int qr = lane >> 2, qt = lane & 3;
    size_t orow = ((size_t)b * 2048 + qrow + qr) * 1024 + h * 64 + qt * 16;
    *(s16x8*)&ao[orow]     = ld8(&Pw[qr * LDP + qt * 16]);
    *(s16x8*)&ao[orow + 8] = ld8(&Pw[qr * LDP + qt * 16 + 8]);
}

// ---------------------------------------------------------------------------
// Output projection: OUT[4096][1024](fp32) = AO(bf16) * Wo(bf16)^T.
// ---------------------------------------------------------------------------
__global__ __launch_bounds__(256) void out_gemm(
        const unsigned short* __restrict__ A, const unsigned short* __restrict__ Bm,
        float* __restrict__ OUT) {
    __shared__ unsigned short As[2][128 * 32];
    __shared__ unsigned short Bs[2][64 * 32];
    const int tid = threadIdx.x, lane = tid & 63, wave = tid >> 6;  // 0..3
    const int l15 = lane & 15, l4 = lane >> 4;
    const int wm = wave * 32;
    const int m0 = blockIdx.y * 128, n0 = blockIdx.x * 64;

    f32x4 acc[2][4];
    for (int i = 0; i < 2; i++)
        for (int j = 0; j < 4; j++) acc[i][j] = (f32x4){0.f, 0.f, 0.f, 0.f};

    const unsigned short* aptr = &A[(size_t)(m0 + wave * 32 + (lane >> 2)) * 1024 + (lane & 3) * 8];
    const unsigned short* bptr = &Bm[(size_t)(n0 + wave * 16 + (lane >> 2)) * 1024 + (lane & 3) * 8];

    for (int k0 = 0; k0 < 1024; k0 += 64) {
        __syncthreads();
        for (int c = 0; c < 2; c++) {
            glds16(aptr + k0 + c * 32, &As[c][(wave * 32) * 32]);
            glds16(aptr + k0 + c * 32 + 16 * 1024, &As[c][(wave * 32 + 16) * 32]);
            glds16(bptr + k0 + c * 32, &Bs[c][(wave * 16) * 32]);
        }
        __syncthreads();
        for (int c = 0; c < 2; c++) {
            s16x8 af[2], bf[4];
            for (int mt = 0; mt < 2; mt++) af[mt] = ld8a(&As[c][(wm + mt * 16 + l15) * 32 + l4 * 8]);
            for (int nt = 0; nt < 4; nt++) bf[nt] = ld8a(&Bs[c][(nt * 16 + l15) * 32 + l4 * 8]);
            for (int mt = 0; mt < 2; mt++)
                for (int nt = 0; nt < 4; nt++)
                    acc[mt][nt] = mfma16(af[mt], bf[nt], acc[mt][nt]);
        }
    }

    for (int mt = 0; mt < 2; mt++)
        for (int nt = 0; nt < 4; nt++)
            for (int r = 0; r < 4; r++) {
                int gm = m0 + wm + mt * 16 + l4 * 4 + r;
                int gn = n0 + nt * 16 + l15;
                OUT[(size_t)gm * 1024 + gn] = acc[mt][nt][r];
            }
}

// ---------------------------------------------------------------------------
extern "C" void kernel_launch(void* const* d_in, const int* in_sizes, int n_in,
                              void* d_out, int out_size, void* d_ws, size_t ws_size,
                              hipStream_t stream) {
    (void)in_sizes; (void)n_in; (void)out_size; (void)ws_size;
    const float* x    = (const float*)d_in[0];   // [2,2048,1024]
    const float* Wqkv = (const float*)d_in[1];   // [3072,1024]
    const float* Wout = (const float*)d_in[2];   // [1024,1024]
    float* out = (float*)d_out;                  // [2,2048,1024] fp32

    unsigned short* q_ws = (unsigned short*)d_ws;
    unsigned short* k_ws = q_ws + (size_t)4 * 1024 * 1024;
    unsigned short* v_ws = k_ws + (size_t)4 * 1024 * 1024;
    unsigned short* xb   = v_ws + (size_t)4 * 1024 * 1024;  // 8 MB
    unsigned short* ao   = xb;                              // born in attn, xb dead
    unsigned short* wqb  = (unsigned short*)d_out;          // 6 MB scratch in d_out
    unsigned short* wob  = q_ws;                            // 2 MB, written after attn

    const int n4x = 2 * 2048 * 1024 / 4, n4w = 3072 * 1024 / 4;
    convf2b2<<<(n4x + n4w + 255) / 256, 256, 0, stream>>>(x, xb, n4x, Wqkv, wqb, n4w);
    qkv_gemm<<<dim3(24, 32), 512, 0, stream>>>(xb, wqb, q_ws, k_ws, v_ws);
    attn<<<dim3(512), 512, 0, stream>>>(q_ws, k_ws, v_ws, ao);
    convf2b<<<1024, 256, 0, stream>>>(Wout, wob, 1024 * 1024 / 4);
    out_gemm<<<dim3(16, 32), 256, 0, stream>>>(ao, wob, out);
}